// Round 8
// baseline (1569.840 us; speedup 1.0000x reference)
//
#include <hip/hip_runtime.h>

#define TT 512
#define D 4
#define NIV (TT / D)   // 128 intervals of real work per stage

typedef __attribute__((ext_vector_type(8))) short bf16x8;
typedef __attribute__((ext_vector_type(4))) float f32x4;

__device__ inline short f2bf(float f) {
    // round-to-nearest-even fp32 -> bf16 (values bounded; no NaN path needed)
    unsigned u = __float_as_uint(f);
    u += 0x7FFFu + ((u >> 16) & 1u);
    return (short)(u >> 16);
}

#define MFMA16(a, b, c) __builtin_amdgcn_mfma_f32_16x16x32_bf16((a), (b), (c), 0, 0, 0)

// 768 threads = 12 waves = 6 pipeline stages x 2 row-pairs. grid=256, 1 WG/CU.
// Stages: 0=ih0 (x@Wih0), 1=hh0, 2=ih1, 3=hh1, 4=ih2, 5=hh2. Stage s lags
// s*D timesteps; ONE barrier per D-step interval (133 barriers vs 514).
// Key property: the serial recurrence h(t)->h(t+1) lives INSIDE each hh wave
// (which owns 2 whole batch rows, all 64 units): it writes h(t) to its ring
// slot and reads back its own A-frags intra-wave (per-wave DS ordering, no
// barrier). Cross-wave traffic is the feed-forward gx / h stream, double-
// buffered by interval parity in LDS. Weights are split per stage (ih waves
// hold Wih, hh waves hold Whh: 24 frags = 96 VGPRs each) so everything fits
// 3 waves/SIMD with no spill (R7 lesson: both matrices resident -> spills).
// A-frag rows replicated 8x (A row = n_>=8): lane (q,n_) C reg0 =
// (row q>=2, col tile*16+n_). Gate transcendentals via exp2 with weight/bias
// pre-scaling (-log2e for r/z, 2*log2e for n) — R5-verified numerics.
__global__ __launch_bounds__(768, 1)
void gru_fused(const float* __restrict__ x,
               const float* __restrict__ Wih0, const float* __restrict__ Whh0,
               const float* __restrict__ bih0, const float* __restrict__ bhh0,
               const float* __restrict__ Wih1, const float* __restrict__ Whh1,
               const float* __restrict__ bih1, const float* __restrict__ bhh1,
               const float* __restrict__ Wih2, const float* __restrict__ Whh2,
               const float* __restrict__ bih2, const float* __restrict__ bhh2,
               const float* __restrict__ fc1w, const float* __restrict__ fc1b,
               const float* __restrict__ fc2w, const float* __restrict__ fc2b,
               float* __restrict__ out)
{
    // h rings: [layer][parity][rp][d][2 rows x 72 shorts] bf16 (~13.8 KB).
    // Row stride 72 shorts = 144 B keeps the two rows' granules on
    // different banks; 16B-aligned frag reads.
    __shared__ __align__(16) short hring[3][2][2][D][2 * 72];
    // gx rings: [layer][parity][rp][d][row][n_][m0..11] f32 (72 KB).
    // Layout chosen so producer writes and consumer reads are both 3x b128.
    __shared__ __align__(16) float gxb[3][2][2][D][2][16][12];
    __shared__ float h2out[4][64];
    __shared__ float fcz[4][32];

    const int tid = threadIdx.x;
    const int l   = tid & 63;
    const int wid = tid >> 6;                                    // 0..11
    const int stage = __builtin_amdgcn_readfirstlane(wid >> 1);  // 0..5
    const int rp  = wid & 1;                                     // row pair
    const int n_  = l & 15;
    const int q   = l >> 4;
    const int nrow = n_ >> 3;        // A-replication row (0..1)
    const int crow = q >> 1;         // C row for this lane (0..1)
    const bool wr  = ((q & 1) == 0); // writer lanes (q==0 -> row0, q==2 -> row1)
    const int rbase = blockIdx.x * 4;
    const int Lx = stage >> 1;       // layer index for both stage kinds
    const bool is_hh  = (stage & 1) != 0;
    const bool is_ih0 = (stage == 0);
    const float L2E = 1.44269504088896f;

    const float* Wp = is_hh ? ((Lx == 0) ? Whh0 : (Lx == 1) ? Whh1 : Whh2)
                            : ((Lx == 0) ? Wih0 : (Lx == 1) ? Wih1 : Wih2);
    const float* bi = (Lx == 0) ? bih0 : (Lx == 1) ? bih1 : bih2;
    const float* bh = (Lx == 0) ? bhh0 : (Lx == 1) ? bhh1 : bhh2;

    // ---- resident weight frags: 12 col-tiles (ti = gate*4+mm) x 2 K-halves.
    // B-frag lane layout: col = ti*16+n_, k = kt*32 + q*8 + j. Scale folded.
    bf16x8 wf[24];
#pragma unroll
    for (int ti = 0; ti < 12; ++ti) {
        const int col = (ti >> 2) * 64 + (ti & 3) * 16 + n_;
        const float sc = (ti < 8) ? -L2E : 2.0f * L2E;
#pragma unroll
        for (int kt = 0; kt < 2; ++kt) {
            bf16x8 f;
#pragma unroll
            for (int j = 0; j < 8; ++j) {
                const int k = kt * 32 + q * 8 + j;
                float v;
                if (is_ih0) v = (k < 16) ? Wp[col * 16 + k] : 0.0f;  // K=16 zero-padded
                else        v = Wp[col * 64 + k];
                f[j] = f2bf(v * sc);
            }
            wf[ti * 2 + kt] = f;
        }
    }

    // ---- biases: ih waves fold r/z (bih+bhh) and n's bih into gx;
    //      hh waves keep only bhn (inside r*(...)).
    float bsum[12], bhn_[4];
    if (!is_hh) {
#pragma unroll
        for (int ti = 0; ti < 12; ++ti) {
            const int u2 = (ti & 3) * 16 + n_;
            const int gofs = (ti >> 2) * 64;
            bsum[ti] = (ti < 8) ? -L2E * (bi[gofs + u2] + bh[gofs + u2])
                                : 2.0f * L2E * bi[128 + u2];
        }
    } else {
#pragma unroll
        for (int mm = 0; mm < 4; ++mm) bhn_[mm] = 2.0f * L2E * bh[128 + mm * 16 + n_];
    }

    const f32x4 zf4 = {0.f, 0.f, 0.f, 0.f};
    const bf16x8 zero8 = {0, 0, 0, 0, 0, 0, 0, 0};
    bf16x8 hA0 = zero8, hA1 = zero8;   // hh state: h(-1) = 0, A-frag layout
    bf16x8 xA  = zero8;                // ih0 masked x frag (q>=2 stays zero)
    float hp[4] = {0.f, 0.f, 0.f, 0.f};

    for (int ivl = 0; ivl < NIV + 5; ++ivl) {
        const int p  = ivl & 1;      // produce parity
        const int pc = p ^ 1;        // consume parity (prev interval)
        if (ivl >= stage && ivl < stage + NIV) {
            const int t0 = (ivl - stage) * D;
            if (is_ih0) {
                // ---- stage 0: gx0 = x @ Wih0 (K=16), x direct from global ----
                const float* xb = x + ((size_t)(rbase + rp * 2 + nrow) * TT + t0) * 16 + q * 8;
                f32x4 xl[D][2];
                if (q < 2) {
#pragma unroll
                    for (int d = 0; d < D; ++d) {       // whole interval in flight
                        xl[d][0] = *(const f32x4*)(xb + d * 16);
                        xl[d][1] = *(const f32x4*)(xb + d * 16 + 4);
                    }
                }
#pragma unroll
                for (int d = 0; d < D; ++d) {
                    if (q < 2) {
#pragma unroll
                        for (int j = 0; j < 4; ++j) {
                            xA[j]     = f2bf(xl[d][0][j]);
                            xA[4 + j] = f2bf(xl[d][1][j]);
                        }
                    }
                    float gv[12];
#pragma unroll
                    for (int ti = 0; ti < 12; ++ti) {
                        f32x4 a = MFMA16(xA, wf[ti * 2], zf4);
                        gv[ti] = a[0] + bsum[ti];
                    }
                    if (wr) {
                        float* gp = &gxb[0][p][rp][d][crow][n_][0];
                        *(f32x4*)(gp)     = (f32x4){gv[0], gv[1], gv[2],  gv[3]};
                        *(f32x4*)(gp + 4) = (f32x4){gv[4], gv[5], gv[6],  gv[7]};
                        *(f32x4*)(gp + 8) = (f32x4){gv[8], gv[9], gv[10], gv[11]};
                    }
                }
            } else if (!is_hh) {
                // ---- stages 2,4: gx_L = h^{L-1} @ Wih_L (K=64) ----
#pragma unroll
                for (int d = 0; d < D; ++d) {
                    const short* hs = &hring[Lx - 1][pc][rp][d][0];
                    const bf16x8 a0 = *(const bf16x8*)(hs + nrow * 72 + q * 8);
                    const bf16x8 a1 = *(const bf16x8*)(hs + nrow * 72 + 32 + q * 8);
                    float gv[12];
#pragma unroll
                    for (int ti = 0; ti < 12; ++ti) {
                        f32x4 a = MFMA16(a0, wf[ti * 2], zf4);
                        a = MFMA16(a1, wf[ti * 2 + 1], a);
                        gv[ti] = a[0] + bsum[ti];
                    }
                    if (wr) {
                        float* gp = &gxb[Lx][p][rp][d][crow][n_][0];
                        *(f32x4*)(gp)     = (f32x4){gv[0], gv[1], gv[2],  gv[3]};
                        *(f32x4*)(gp + 4) = (f32x4){gv[4], gv[5], gv[6],  gv[7]};
                        *(f32x4*)(gp + 8) = (f32x4){gv[8], gv[9], gv[10], gv[11]};
                    }
                }
            } else {
                // ---- stages 1,3,5: recurrence, fully wave-local ----
#pragma unroll
                for (int d = 0; d < D; ++d) {
                    const float* gp = &gxb[Lx][pc][rp][d][crow][n_][0];
                    const f32x4 gr = *(const f32x4*)(gp);
                    const f32x4 gz = *(const f32x4*)(gp + 4);
                    const f32x4 gn = *(const f32x4*)(gp + 8);
                    float rr[4], zz[4];
#pragma unroll
                    for (int mm = 0; mm < 4; ++mm) {
                        f32x4 ar = MFMA16(hA0, wf[mm * 2], zf4);
                        ar = MFMA16(hA1, wf[mm * 2 + 1], ar);
                        f32x4 az = MFMA16(hA0, wf[8 + mm * 2], zf4);
                        az = MFMA16(hA1, wf[8 + mm * 2 + 1], az);
                        rr[mm] = __fdividef(1.0f, 1.0f + exp2f(ar[0] + gr[mm]));
                        zz[mm] = __fdividef(1.0f, 1.0f + exp2f(az[0] + gz[mm]));
                    }
                    float hv[4];
#pragma unroll
                    for (int mm = 0; mm < 4; ++mm) {
                        f32x4 an = MFMA16(hA0, wf[16 + mm * 2], zf4);
                        an = MFMA16(hA1, wf[16 + mm * 2 + 1], an);
                        const float sn = gn[mm] + rr[mm] * (an[0] + bhn_[mm]);
                        const float nn = 1.0f - __fdividef(2.0f, 1.0f + exp2f(sn));
                        hv[mm] = nn + zz[mm] * (hp[mm] - nn);
                        hp[mm] = hv[mm];
                    }
                    // write h(t) to own ring slot, then intra-wave readback of
                    // next step's A-frags (per-wave DS ordering; no barrier)
                    short* os = &hring[Lx][p][rp][d][0];
                    if (wr) {
#pragma unroll
                        for (int mm = 0; mm < 4; ++mm)
                            os[crow * 72 + mm * 16 + n_] = f2bf(hv[mm]);
                    }
                    hA0 = *(const bf16x8*)(os + nrow * 72 + q * 8);
                    hA1 = *(const bf16x8*)(os + nrow * 72 + 32 + q * 8);
                }
            }
        }
        __syncthreads();
    }

    // ---- FC head: stage-5 waves hold h2(T-1): 4 units/lane, row crow ----
    if (stage == 5 && wr) {
#pragma unroll
        for (int mm = 0; mm < 4; ++mm) h2out[rp * 2 + crow][mm * 16 + n_] = hp[mm];
    }
    __syncthreads();
    if (tid < 128) {
        const int row = tid >> 5, uu = tid & 31;
        float acc = fc1b[uu];
#pragma unroll
        for (int k = 0; k < 64; ++k) acc += h2out[row][k] * fc1w[uu * 64 + k];
        fcz[row][uu] = fmaxf(acc, 0.0f);
    }
    __syncthreads();
    if (tid < 4) {
        float y = fc2b[0];
#pragma unroll
        for (int uu = 0; uu < 32; ++uu) y += fcz[tid][uu] * fc2w[uu];
        out[rbase + tid] = y;
    }
}

extern "C" void kernel_launch(void* const* d_in, const int* in_sizes, int n_in,
                              void* d_out, int out_size, void* d_ws, size_t ws_size,
                              hipStream_t stream) {
    (void)in_sizes; (void)n_in; (void)d_ws; (void)ws_size; (void)out_size;
    gru_fused<<<dim3(256), dim3(768), 0, stream>>>(
        (const float*)d_in[0],
        (const float*)d_in[1],  (const float*)d_in[2],  (const float*)d_in[3],  (const float*)d_in[4],
        (const float*)d_in[5],  (const float*)d_in[6],  (const float*)d_in[7],  (const float*)d_in[8],
        (const float*)d_in[9],  (const float*)d_in[10], (const float*)d_in[11], (const float*)d_in[12],
        (const float*)d_in[13], (const float*)d_in[14], (const float*)d_in[15], (const float*)d_in[16],
        (float*)d_out);
}

// Round 9
// 751.996 us; speedup vs baseline: 2.0876x; 2.0876x over previous
//
#include <hip/hip_runtime.h>

#define TT 512
#define D 4
#define NIV (TT / D)   // 128 intervals of real work per stage

typedef __attribute__((ext_vector_type(8))) short bf16x8;
typedef __attribute__((ext_vector_type(4))) float f32x4;

__device__ inline short f2bf(float f) {
    // round-to-nearest-even fp32 -> bf16 (values bounded; no NaN path needed)
    unsigned u = __float_as_uint(f);
    u += 0x7FFFu + ((u >> 16) & 1u);
    return (short)(u >> 16);
}

#define MFMA16(a, b, c) __builtin_amdgcn_mfma_f32_16x16x32_bf16((a), (b), (c), 0, 0, 0)

// 384 threads = 6 waves = 6 pipeline stages, each owning ALL 4 batch rows.
// grid = 256 = 1 WG/CU. Stages: 0=ih0, 1=hh0, 2=ih1, 3=hh1, 4=ih2, 5=hh2.
// Stage s lags s*D timesteps; ONE barrier per D-step interval (133 vs 514).
// R8's structure, fixed: 12-wave WGs cap the unified reg file at ~170/wave
// (3 waves/SIMD) -> wf[24]+temps spilled (381 MB scratch traffic). 6 waves
// -> 2 waves/SIMD -> 256-reg cap -> the ~170-reg working set fits, no spill.
// The serial recurrence lives INSIDE each hh wave: it writes h(t) to its
// ring slot and reads back its own A-frags intra-wave (per-wave DS FIFO
// ordering, HW-proven in R0) — h never crosses a barrier. Cross-wave traffic
// is the feed-forward gx / h stream, double-buffered by interval parity.
// A-frag rows replicated 4x (A row r -> batch row r>>2): lane (q,n_) C reg0
// = (batch row q, col tile*16+n_); lane owns units {mm*16+n_}, row q.
// Gate transcendentals via exp2 with weight/bias pre-scaling (-log2e for
// r/z, 2*log2e for n) — R5/R8-verified numerics (absmax 4.88e-4).
__global__ __launch_bounds__(384, 1)
void gru_fused(const float* __restrict__ x,
               const float* __restrict__ Wih0, const float* __restrict__ Whh0,
               const float* __restrict__ bih0, const float* __restrict__ bhh0,
               const float* __restrict__ Wih1, const float* __restrict__ Whh1,
               const float* __restrict__ bih1, const float* __restrict__ bhh1,
               const float* __restrict__ Wih2, const float* __restrict__ Whh2,
               const float* __restrict__ bih2, const float* __restrict__ bhh2,
               const float* __restrict__ fc1w, const float* __restrict__ fc1b,
               const float* __restrict__ fc2w, const float* __restrict__ fc2b,
               float* __restrict__ out)
{
    // h rings: [layer][parity][d][4 rows x 72 shorts] bf16 (13.5 KB).
    // Row stride 72 shorts = 144 B -> 16B-aligned frags, ~2-way banks.
    __shared__ __align__(16) short hring[3][2][D][4 * 72];
    // gx rings: [layer][parity][d][row][n_][12 gates] f32 (72 KB).
    // 12-word lane stride: b128 accesses are bank-conflict-free.
    __shared__ __align__(16) float gxb[3][2][D][4][16][12];
    __shared__ float h2out[4][64];
    __shared__ float fcz[4][32];

    const int tid = threadIdx.x;
    const int l   = tid & 63;
    const int wid = tid >> 6;                                 // 0..5
    const int stage = __builtin_amdgcn_readfirstlane(wid);    // scalar stage id
    const int n_  = l & 15;
    const int q   = l >> 4;          // C row = batch row; also k-slice for frags
    const int ar  = n_ >> 2;         // A-replication batch row (0..3)
    const int rbase = blockIdx.x * 4;
    const int Lx = stage >> 1;       // layer index
    const bool is_hh  = (stage & 1) != 0;
    const bool is_ih0 = (stage == 0);
    const float L2E = 1.44269504088896f;

    const float* Wp = is_hh ? ((Lx == 0) ? Whh0 : (Lx == 1) ? Whh1 : Whh2)
                            : ((Lx == 0) ? Wih0 : (Lx == 1) ? Wih1 : Wih2);
    const float* bi = (Lx == 0) ? bih0 : (Lx == 1) ? bih1 : bih2;
    const float* bh = (Lx == 0) ? bhh0 : (Lx == 1) ? bhh1 : bhh2;

    // ---- resident weight frags: 12 col-tiles (ti = gate*4+mm) x 2 K-halves.
    // B-frag lane layout: col = (ti>>2)*64 + (ti&3)*16 + n_, k = kt*32+q*8+j.
    bf16x8 wf[24];
#pragma unroll
    for (int ti = 0; ti < 12; ++ti) {
        const int col = (ti >> 2) * 64 + (ti & 3) * 16 + n_;
        const float sc = (ti < 8) ? -L2E : 2.0f * L2E;
#pragma unroll
        for (int kt = 0; kt < 2; ++kt) {
            bf16x8 f;
#pragma unroll
            for (int j = 0; j < 8; ++j) {
                const int k = kt * 32 + q * 8 + j;
                float v;
                if (is_ih0) v = (k < 16) ? Wp[col * 16 + k] : 0.0f;  // K=16 padded
                else        v = Wp[col * 64 + k];
                f[j] = f2bf(v * sc);
            }
            wf[ti * 2 + kt] = f;
        }
    }

    // ---- biases: ih waves fold r/z (bih+bhh) and n's bih into gx;
    //      hh waves keep only bhn (inside r*(...)).
    float bsum[12], bhn_[4];
    if (!is_hh) {
#pragma unroll
        for (int ti = 0; ti < 12; ++ti) {
            const int u2 = (ti & 3) * 16 + n_;
            const int gofs = (ti >> 2) * 64;
            bsum[ti] = (ti < 8) ? -L2E * (bi[gofs + u2] + bh[gofs + u2])
                                : 2.0f * L2E * bi[128 + u2];
        }
    } else {
#pragma unroll
        for (int mm = 0; mm < 4; ++mm) bhn_[mm] = 2.0f * L2E * bh[128 + mm * 16 + n_];
    }

    const f32x4 zf4 = {0.f, 0.f, 0.f, 0.f};
    const bf16x8 zero8 = {0, 0, 0, 0, 0, 0, 0, 0};
    bf16x8 hA0 = zero8, hA1 = zero8;   // hh state: h(-1)=0, A-frag layout, in regs
    float hp[4] = {0.f, 0.f, 0.f, 0.f};

    for (int ivl = 0; ivl < NIV + 5; ++ivl) {
        const int p  = ivl & 1;      // produce parity
        const int pc = p ^ 1;        // consume parity (prev interval)
        if (ivl >= stage && ivl < stage + NIV) {
            const int t0 = (ivl - stage) * D;
            if (is_ih0) {
                // ---- stage 0: gx0 = x @ Wih0 (K=16), x direct from global ----
                const float* xb = x + ((size_t)(rbase + ar) * TT + t0) * 16 + q * 8;
                f32x4 xl[D][2];
                if (q < 2) {
#pragma unroll
                    for (int d = 0; d < D; ++d) {       // whole interval in flight
                        xl[d][0] = *(const f32x4*)(xb + d * 16);
                        xl[d][1] = *(const f32x4*)(xb + d * 16 + 4);
                    }
                }
#pragma unroll
                for (int d = 0; d < D; ++d) {
                    bf16x8 xA = zero8;
                    if (q < 2) {
#pragma unroll
                        for (int j = 0; j < 4; ++j) {
                            xA[j]     = f2bf(xl[d][0][j]);
                            xA[4 + j] = f2bf(xl[d][1][j]);
                        }
                    }
                    float gv[12];
#pragma unroll
                    for (int ti = 0; ti < 12; ++ti) {
                        f32x4 a = MFMA16(xA, wf[ti * 2], zf4);
                        gv[ti] = a[0] + bsum[ti];
                    }
                    float* gp = &gxb[0][p][d][q][n_][0];
                    *(f32x4*)(gp)     = (f32x4){gv[0], gv[1], gv[2],  gv[3]};
                    *(f32x4*)(gp + 4) = (f32x4){gv[4], gv[5], gv[6],  gv[7]};
                    *(f32x4*)(gp + 8) = (f32x4){gv[8], gv[9], gv[10], gv[11]};
                }
            } else if (!is_hh) {
                // ---- stages 2,4: gx_L = h^{L-1} @ Wih_L (K=64) ----
#pragma unroll
                for (int d = 0; d < D; ++d) {
                    const short* hs = &hring[Lx - 1][pc][d][0];
                    const bf16x8 a0 = *(const bf16x8*)(hs + ar * 72 + q * 8);
                    const bf16x8 a1 = *(const bf16x8*)(hs + ar * 72 + 32 + q * 8);
                    float gv[12];
#pragma unroll
                    for (int ti = 0; ti < 12; ++ti) {
                        f32x4 a = MFMA16(a0, wf[ti * 2], zf4);
                        a = MFMA16(a1, wf[ti * 2 + 1], a);
                        gv[ti] = a[0] + bsum[ti];
                    }
                    float* gp = &gxb[Lx][p][d][q][n_][0];
                    *(f32x4*)(gp)     = (f32x4){gv[0], gv[1], gv[2],  gv[3]};
                    *(f32x4*)(gp + 4) = (f32x4){gv[4], gv[5], gv[6],  gv[7]};
                    *(f32x4*)(gp + 8) = (f32x4){gv[8], gv[9], gv[10], gv[11]};
                }
            } else {
                // ---- stages 1,3,5: recurrence, fully wave-local ----
#pragma unroll
                for (int d = 0; d < D; ++d) {
                    const float* gp = &gxb[Lx][pc][d][q][n_][0];
                    const f32x4 gr = *(const f32x4*)(gp);
                    const f32x4 gz = *(const f32x4*)(gp + 4);
                    const f32x4 gn = *(const f32x4*)(gp + 8);
                    float rr[4], zz[4];
#pragma unroll
                    for (int mm = 0; mm < 4; ++mm) {
                        f32x4 ca = MFMA16(hA0, wf[mm * 2], zf4);
                        ca = MFMA16(hA1, wf[mm * 2 + 1], ca);
                        f32x4 cb = MFMA16(hA0, wf[8 + mm * 2], zf4);
                        cb = MFMA16(hA1, wf[8 + mm * 2 + 1], cb);
                        rr[mm] = __fdividef(1.0f, 1.0f + exp2f(ca[0] + gr[mm]));
                        zz[mm] = __fdividef(1.0f, 1.0f + exp2f(cb[0] + gz[mm]));
                    }
                    short* os = &hring[Lx][p][d][0];
#pragma unroll
                    for (int mm = 0; mm < 4; ++mm) {
                        f32x4 cn = MFMA16(hA0, wf[16 + mm * 2], zf4);
                        cn = MFMA16(hA1, wf[16 + mm * 2 + 1], cn);
                        const float sn = gn[mm] + rr[mm] * (cn[0] + bhn_[mm]);
                        const float nn = 1.0f - __fdividef(2.0f, 1.0f + exp2f(sn));
                        const float hv = nn + zz[mm] * (hp[mm] - nn);
                        hp[mm] = hv;
                        os[q * 72 + mm * 16 + n_] = f2bf(hv);
                    }
                    // intra-wave readback of next step's A-frags (no barrier)
                    hA0 = *(const bf16x8*)(os + ar * 72 + q * 8);
                    hA1 = *(const bf16x8*)(os + ar * 72 + 32 + q * 8);
                }
            }
        }
        __syncthreads();
    }

    // ---- FC head: stage-5 wave holds h2(T-1): lane (q,n_) units mm*16+n_ ----
    if (stage == 5) {
#pragma unroll
        for (int mm = 0; mm < 4; ++mm) h2out[q][mm * 16 + n_] = hp[mm];
    }
    __syncthreads();
    if (tid < 128) {
        const int row = tid >> 5, uu = tid & 31;
        float acc = fc1b[uu];
#pragma unroll
        for (int k = 0; k < 64; ++k) acc += h2out[row][k] * fc1w[uu * 64 + k];
        fcz[row][uu] = fmaxf(acc, 0.0f);
    }
    __syncthreads();
    if (tid < 4) {
        float y = fc2b[0];
#pragma unroll
        for (int uu = 0; uu < 32; ++uu) y += fcz[tid][uu] * fc2w[uu];
        out[rbase + tid] = y;
    }
}

extern "C" void kernel_launch(void* const* d_in, const int* in_sizes, int n_in,
                              void* d_out, int out_size, void* d_ws, size_t ws_size,
                              hipStream_t stream) {
    (void)in_sizes; (void)n_in; (void)d_ws; (void)ws_size; (void)out_size;
    gru_fused<<<dim3(256), dim3(384), 0, stream>>>(
        (const float*)d_in[0],
        (const float*)d_in[1],  (const float*)d_in[2],  (const float*)d_in[3],  (const float*)d_in[4],
        (const float*)d_in[5],  (const float*)d_in[6],  (const float*)d_in[7],  (const float*)d_in[8],
        (const float*)d_in[9],  (const float*)d_in[10], (const float*)d_in[11], (const float*)d_in[12],
        (const float*)d_in[13], (const float*)d_in[14], (const float*)d_in[15], (const float*)d_in[16],
        (float*)d_out);
}